// Round 1
// baseline (778.848 us; speedup 1.0000x reference)
//
#include <hip/hip_runtime.h>
#include <hip/hip_fp16.h>

// Problem: B=32, S=2048, D=1024, H=1024
//   qp = query@W2 [B,H]; keys = values@W1 [B,S,H]; scores = tanh(qp+keys)@v [B,S]
//   w = softmax(scores); ctx = w@values [B,D]. Outputs: ctx (32768) ++ w (65536).

typedef _Float16 v8h __attribute__((ext_vector_type(8)));
typedef float   v4f __attribute__((ext_vector_type(4)));

#define B_DIM 32
#define S_DIM 2048
#define D_DIM 1024
#define H_DIM 1024

// workspace layout (bytes); total ~4.4 MiB
#define WS_W1T    0u                      // [H][D] fp16 = 2 MiB
#define WS_QP     2097152u                // [B][H] fp32 = 128 KiB
#define WS_SCORES (WS_QP + 131072u)       // [B][S] fp32 = 256 KiB
#define WS_PART   (WS_SCORES + 262144u)   // [B][16][D] fp32 = 2 MiB

// ---------------- K0a: W1 [D,H] fp32 -> W1T [H,D] fp16 ----------------
__global__ void k_w1t(const float* __restrict__ W1, _Float16* __restrict__ w1t) {
    __shared__ float t[64][65];
    int h0 = blockIdx.x * 64, d0 = blockIdx.y * 64;
    int tid = threadIdx.x;
    #pragma unroll
    for (int i = 0; i < 16; ++i) {
        int idx = i * 256 + tid;
        int dd = idx >> 6, hh = idx & 63;
        t[dd][hh] = W1[(size_t)(d0 + dd) * H_DIM + h0 + hh];
    }
    __syncthreads();
    #pragma unroll
    for (int i = 0; i < 16; ++i) {
        int idx = i * 256 + tid;
        int hh = idx >> 6, dd = idx & 63;
        w1t[(size_t)(h0 + hh) * D_DIM + d0 + dd] = (_Float16)t[dd][hh];
    }
}

// ---------------- K0b: qp = query @ W2 (fp32) ----------------
__global__ void k_qp(const float* __restrict__ query, const float* __restrict__ W2,
                     float* __restrict__ qp) {
    __shared__ float q[1024];
    int b = blockIdx.y, hc = blockIdx.x, tid = threadIdx.x;
    #pragma unroll
    for (int i = 0; i < 4; ++i) q[i * 256 + tid] = query[b * D_DIM + i * 256 + tid];
    __syncthreads();
    int h = hc * 256 + tid;
    float acc = 0.f;
    #pragma unroll 8
    for (int d = 0; d < D_DIM; ++d) acc += q[d] * W2[(size_t)d * H_DIM + h];
    qp[b * H_DIM + h] = acc;
}

// ---------------- K1: fused scores GEMM ----------------
// block = 256 thr (4 waves, 2x2), tile 128 rows x 128 cols per N-pass, BK=64
#define SA 88   // LDS row stride in halves: 176 B -> 2-way bank alias only (free), 16B aligned

__global__ __launch_bounds__(256, 2) void k_scores(
        const float* __restrict__ values, const _Float16* __restrict__ w1t,
        const float* __restrict__ qp, const float* __restrict__ v,
        float* __restrict__ scores) {
    __shared__ _Float16 As[128 * SA];
    __shared__ _Float16 Bs[128 * SA];
    __shared__ float s_scores[128];

    int tid = threadIdx.x;
    int wid = tid >> 6, lane = tid & 63;
    int quad = lane >> 4, l15 = lane & 15;
    int wm = wid >> 1, wn = wid & 1;
    int b  = blockIdx.x >> 4;
    int m0 = (blockIdx.x & 15) * 128;

    if (tid < 128) s_scores[tid] = 0.f;
    __syncthreads();

    const size_t arow = ((size_t)b * S_DIM + m0) * D_DIM;

    for (int np = 0; np < 8; ++np) {
        int n0 = np * 128;
        v4f acc[4][4];
        #pragma unroll
        for (int i = 0; i < 4; ++i)
            #pragma unroll
            for (int j = 0; j < 4; ++j) acc[i][j] = (v4f){0.f, 0.f, 0.f, 0.f};

        for (int kt = 0; kt < 16; ++kt) {
            int k0 = kt * 64;
            // stage A tile: values fp32 -> fp16 LDS [m][k]
            #pragma unroll
            for (int i = 0; i < 4; ++i) {
                int c = i * 256 + tid;
                int m = c >> 3, k8 = c & 7;
                const float* src = values + arow + (size_t)m * D_DIM + k0 + k8 * 8;
                float4 f0 = *(const float4*)src;
                float4 f1 = *(const float4*)(src + 4);
                v8h hv;
                hv[0] = (_Float16)f0.x; hv[1] = (_Float16)f0.y;
                hv[2] = (_Float16)f0.z; hv[3] = (_Float16)f0.w;
                hv[4] = (_Float16)f1.x; hv[5] = (_Float16)f1.y;
                hv[6] = (_Float16)f1.z; hv[7] = (_Float16)f1.w;
                *(v8h*)(&As[m * SA + k8 * 8]) = hv;
            }
            // stage B tile: W1T fp16 -> LDS [n][k]
            #pragma unroll
            for (int i = 0; i < 4; ++i) {
                int c = i * 256 + tid;
                int n = c >> 3, k8 = c & 7;
                v8h hv = *(const v8h*)(w1t + (size_t)(n0 + n) * D_DIM + k0 + k8 * 8);
                *(v8h*)(&Bs[n * SA + k8 * 8]) = hv;
            }
            __syncthreads();
            #pragma unroll
            for (int kk = 0; kk < 2; ++kk) {
                v8h af[4], bf[4];
                #pragma unroll
                for (int mt = 0; mt < 4; ++mt)
                    af[mt] = *(const v8h*)(&As[(wm * 64 + mt * 16 + l15) * SA + kk * 32 + quad * 8]);
                #pragma unroll
                for (int nt = 0; nt < 4; ++nt)
                    bf[nt] = *(const v8h*)(&Bs[(wn * 64 + nt * 16 + l15) * SA + kk * 32 + quad * 8]);
                #pragma unroll
                for (int mt = 0; mt < 4; ++mt)
                    #pragma unroll
                    for (int nt = 0; nt < 4; ++nt)
                        acc[mt][nt] = __builtin_amdgcn_mfma_f32_16x16x32_f16(
                            af[mt], bf[nt], acc[mt][nt], 0, 0, 0);
            }
            __syncthreads();
        }
        // epilogue: scores += sum_n tanh(acc + qp[n]) * v[n]
        float qpv[4], vv[4];
        #pragma unroll
        for (int nt = 0; nt < 4; ++nt) {
            int ng = n0 + wn * 64 + nt * 16 + l15;
            qpv[nt] = qp[b * H_DIM + ng];
            vv[nt]  = v[ng];
        }
        #pragma unroll
        for (int mt = 0; mt < 4; ++mt) {
            #pragma unroll
            for (int r = 0; r < 4; ++r) {
                float s = 0.f;
                #pragma unroll
                for (int nt = 0; nt < 4; ++nt) {
                    float x = acc[mt][nt][r] + qpv[nt];
                    float e = __expf(2.f * x);           // tanh(x) = 1 - 2/(e^{2x}+1)
                    float t = 1.f - 2.f / (e + 1.f);     // saturates correctly at +-inf
                    s += t * vv[nt];
                }
                s += __shfl_xor(s, 1);
                s += __shfl_xor(s, 2);
                s += __shfl_xor(s, 4);
                s += __shfl_xor(s, 8);
                if (l15 == 0)
                    atomicAdd(&s_scores[wm * 64 + mt * 16 + quad * 4 + r], s);
            }
        }
    }
    __syncthreads();
    if (tid < 128) scores[(size_t)b * S_DIM + m0 + tid] = s_scores[tid];
}

// ---------------- K2: row softmax -> attention weights (output 1) ----------------
__global__ void k_softmax(const float* __restrict__ scores, float* __restrict__ wout) {
    __shared__ float red[256];
    int b = blockIdx.x, tid = threadIdx.x;
    float ls[8];
    float lmax = -1e30f;
    #pragma unroll
    for (int i = 0; i < 8; ++i) {
        ls[i] = scores[b * S_DIM + i * 256 + tid];
        lmax = fmaxf(lmax, ls[i]);
    }
    red[tid] = lmax; __syncthreads();
    for (int st = 128; st > 0; st >>= 1) {
        if (tid < st) red[tid] = fmaxf(red[tid], red[tid + st]);
        __syncthreads();
    }
    float rowmax = red[0]; __syncthreads();
    float lsum = 0.f;
    #pragma unroll
    for (int i = 0; i < 8; ++i) { ls[i] = __expf(ls[i] - rowmax); lsum += ls[i]; }
    red[tid] = lsum; __syncthreads();
    for (int st = 128; st > 0; st >>= 1) {
        if (tid < st) red[tid] += red[tid + st];
        __syncthreads();
    }
    float inv = 1.f / red[0];
    #pragma unroll
    for (int i = 0; i < 8; ++i) wout[b * S_DIM + i * 256 + tid] = ls[i] * inv;
}

// ---------------- K3: context partials over S-chunks ----------------
__global__ void k_ctx_part(const float* __restrict__ values, const float* __restrict__ w,
                           float* __restrict__ part) {
    int b = blockIdx.x >> 4, sc = blockIdx.x & 15, tid = threadIdx.x;
    float4 acc = {0.f, 0.f, 0.f, 0.f};
    size_t base = ((size_t)b * S_DIM + sc * 128) * D_DIM;
    for (int s = 0; s < 128; ++s) {
        float ww = w[b * S_DIM + sc * 128 + s];
        float4 val = *(const float4*)(values + base + (size_t)s * D_DIM + tid * 4);
        acc.x += ww * val.x; acc.y += ww * val.y;
        acc.z += ww * val.z; acc.w += ww * val.w;
    }
    *(float4*)(part + (size_t)(b * 16 + sc) * D_DIM + tid * 4) = acc;
}

// ---------------- K4: reduce partials -> context (output 0) ----------------
__global__ void k_ctx_reduce(const float* __restrict__ part, float* __restrict__ ctx) {
    int o = blockIdx.x * 256 + threadIdx.x;
    int b = o >> 10, d = o & 1023;
    float s = 0.f;
    #pragma unroll
    for (int sc = 0; sc < 16; ++sc) s += part[(size_t)(b * 16 + sc) * D_DIM + d];
    ctx[o] = s;
}

extern "C" void kernel_launch(void* const* d_in, const int* in_sizes, int n_in,
                              void* d_out, int out_size, void* d_ws, size_t ws_size,
                              hipStream_t stream) {
    const float* query  = (const float*)d_in[0];
    const float* values = (const float*)d_in[1];
    const float* W1     = (const float*)d_in[2];
    const float* W2     = (const float*)d_in[3];
    const float* v      = (const float*)d_in[4];

    char* ws = (char*)d_ws;
    _Float16* w1t = (_Float16*)(ws + WS_W1T);
    float* qp     = (float*)(ws + WS_QP);
    float* scores = (float*)(ws + WS_SCORES);
    float* part   = (float*)(ws + WS_PART);

    float* ctx  = (float*)d_out;            // [32, 1024]
    float* wout = (float*)d_out + 32768;    // [32, 2048]

    k_w1t<<<dim3(16, 16), 256, 0, stream>>>(W1, w1t);
    k_qp<<<dim3(4, 32), 256, 0, stream>>>(query, W2, qp);
    k_scores<<<dim3(512), 256, 0, stream>>>(values, w1t, qp, v, scores);
    k_softmax<<<dim3(32), 256, 0, stream>>>(scores, wout);
    k_ctx_part<<<dim3(512), 256, 0, stream>>>(values, wout, part);
    k_ctx_reduce<<<dim3(128), 256, 0, stream>>>(part, ctx);
}

// Round 2
// 693.376 us; speedup vs baseline: 1.1233x; 1.1233x over previous
//
#include <hip/hip_runtime.h>
#include <hip/hip_fp16.h>

// Problem: B=32, S=2048, D=1024, H=1024
//   qp = query@W2 [B,H]; keys = values@W1 [B,S,H]; scores = tanh(qp+keys)@v [B,S]
//   w = softmax(scores); ctx = w@values [B,D]. Outputs: ctx (32768) ++ w (65536).

typedef _Float16 v8h __attribute__((ext_vector_type(8)));
typedef _Float16 v4h __attribute__((ext_vector_type(4)));
typedef float   v4f __attribute__((ext_vector_type(4)));

#define B_DIM 32
#define S_DIM 2048
#define D_DIM 1024
#define H_DIM 1024

// fp16-values workspace layout (bytes)
#define WS_V16    0u                       // [B][S][D] fp16 = 128 MiB (fits in 256 MiB L3!)
#define WS_W1T    134217728u               // [H][D] fp16 = 2 MiB
#define WS_QP     (WS_W1T + 2097152u)      // [B][H] fp32
#define WS_SCORES (WS_QP + 131072u)        // [B][S] fp32 (atomicAdd target, memset 0)
#define WS_PART   (WS_SCORES + 262144u)    // [B][16][D] fp32
#define WS_NEED   (WS_PART + 2097152u)     // ~132.4 MiB

// async global->LDS, 16B per lane; LDS dest = wave-uniform base + lane*16
__device__ __forceinline__ void gl_lds16(const _Float16* g, _Float16* l) {
    __builtin_amdgcn_global_load_lds(
        (const __attribute__((address_space(1))) void*)g,
        (__attribute__((address_space(3))) void*)l, 16, 0, 0);
}

// ---------------- K0: values fp32 -> fp16 ----------------
__global__ void k_convert(const float* __restrict__ src, _Float16* __restrict__ dst) {
    size_t i = ((size_t)blockIdx.x * 256 + threadIdx.x) * 8;
    float4 f0 = *(const float4*)(src + i);
    float4 f1 = *(const float4*)(src + i + 4);
    v8h hv;
    hv[0] = (_Float16)f0.x; hv[1] = (_Float16)f0.y;
    hv[2] = (_Float16)f0.z; hv[3] = (_Float16)f0.w;
    hv[4] = (_Float16)f1.x; hv[5] = (_Float16)f1.y;
    hv[6] = (_Float16)f1.z; hv[7] = (_Float16)f1.w;
    *(v8h*)(dst + i) = hv;
}

// ---------------- K0a: W1 [D,H] fp32 -> W1T [H,D] fp16 ----------------
__global__ void k_w1t(const float* __restrict__ W1, _Float16* __restrict__ w1t) {
    __shared__ float t[64][65];
    int h0 = blockIdx.x * 64, d0 = blockIdx.y * 64;
    int tid = threadIdx.x;
    #pragma unroll
    for (int i = 0; i < 16; ++i) {
        int idx = i * 256 + tid;
        int dd = idx >> 6, hh = idx & 63;
        t[dd][hh] = W1[(size_t)(d0 + dd) * H_DIM + h0 + hh];
    }
    __syncthreads();
    #pragma unroll
    for (int i = 0; i < 16; ++i) {
        int idx = i * 256 + tid;
        int hh = idx >> 6, dd = idx & 63;
        w1t[(size_t)(h0 + hh) * D_DIM + d0 + dd] = (_Float16)t[dd][hh];
    }
}

// ---------------- K0b: qp = query @ W2 (fp32, precision-critical) ----------------
__global__ void k_qp(const float* __restrict__ query, const float* __restrict__ W2,
                     float* __restrict__ qp) {
    __shared__ float q[1024];
    int b = blockIdx.y, hc = blockIdx.x, tid = threadIdx.x;
    #pragma unroll
    for (int i = 0; i < 4; ++i) q[i * 256 + tid] = query[b * D_DIM + i * 256 + tid];
    __syncthreads();
    int h = hc * 256 + tid;
    float acc = 0.f;
    #pragma unroll 8
    for (int d = 0; d < D_DIM; ++d) acc += q[d] * W2[(size_t)d * H_DIM + h];
    qp[b * H_DIM + h] = acc;
}

// ---------------- K1: fused scores GEMM ----------------
// grid = B(32) x mtiles(16) x np(8) = 4096 blocks, 256 thr (2x2 waves)
// tile 128(m) x 128(n) x K=1024, BK=64. LDS rows = 64 halves (128 B), XOR-swizzled
// (kslot ^ row&7) so global_load_lds (no padding allowed) still gives balanced
// ds_read_b128 fragment reads (8 lanes per 4-bank group = minimum serialization).
template<bool AF16>
__global__ __launch_bounds__(256) void k_scores(
        const float* __restrict__ values, const _Float16* __restrict__ values16,
        const _Float16* __restrict__ w1t, const float* __restrict__ qp,
        const float* __restrict__ v, float* __restrict__ scores) {
    __shared__ _Float16 As[128 * 64];
    __shared__ _Float16 Bs[128 * 64];
    __shared__ float s_scores[128];

    int tid = threadIdx.x;
    int wid = tid >> 6, lane = tid & 63;
    int quad = lane >> 4, l15 = lane & 15;
    int wm = wid >> 1, wn = wid & 1;

    int idx = blockIdx.x;
    int np  = idx & 7;
    int mtb = idx >> 3;
    int b   = mtb >> 4;
    int m0  = (mtb & 15) * 128;
    int n0  = np * 128;

    if (tid < 128) s_scores[tid] = 0.f;

    const size_t arow = ((size_t)b * S_DIM + m0) * D_DIM;

    v4f acc[4][4];
    #pragma unroll
    for (int i = 0; i < 4; ++i)
        #pragma unroll
        for (int j = 0; j < 4; ++j) acc[i][j] = (v4f){0.f, 0.f, 0.f, 0.f};

    for (int kt = 0; kt < 16; ++kt) {
        int k0 = kt * 64;
        if (AF16) {
            #pragma unroll
            for (int i = 0; i < 4; ++i) {
                int brow = i * 32 + wid * 8;
                int row  = brow + (lane >> 3);
                int kg   = (lane & 7) ^ (row & 7);
                gl_lds16(values16 + arow + (size_t)row * D_DIM + k0 + kg * 8, &As[brow * 64]);
                gl_lds16(w1t + (size_t)(n0 + row) * D_DIM + k0 + kg * 8, &Bs[brow * 64]);
            }
        } else {
            #pragma unroll
            for (int i = 0; i < 4; ++i) {
                int brow = i * 32 + wid * 8;
                int row  = brow + (lane >> 3);
                int kg   = (lane & 7) ^ (row & 7);
                gl_lds16(w1t + (size_t)(n0 + row) * D_DIM + k0 + kg * 8, &Bs[brow * 64]);
            }
            #pragma unroll
            for (int i = 0; i < 4; ++i) {
                int c = i * 256 + tid;
                int row = c >> 3, ks = c & 7;
                int kg = ks ^ (row & 7);
                const float* src = values + arow + (size_t)row * D_DIM + k0 + kg * 8;
                float4 f0 = *(const float4*)src;
                float4 f1 = *(const float4*)(src + 4);
                v8h hv;
                hv[0] = (_Float16)f0.x; hv[1] = (_Float16)f0.y;
                hv[2] = (_Float16)f0.z; hv[3] = (_Float16)f0.w;
                hv[4] = (_Float16)f1.x; hv[5] = (_Float16)f1.y;
                hv[6] = (_Float16)f1.z; hv[7] = (_Float16)f1.w;
                *(v8h*)(&As[row * 64 + ks * 8]) = hv;
            }
        }
        __syncthreads();
        #pragma unroll
        for (int kk = 0; kk < 2; ++kk) {
            v8h af[4], bf[4];
            #pragma unroll
            for (int mt = 0; mt < 4; ++mt) {
                int row = wm * 64 + mt * 16 + l15;
                int ph = (kk * 4 + quad) ^ (row & 7);
                af[mt] = *(const v8h*)(&As[row * 64 + ph * 8]);
            }
            #pragma unroll
            for (int nt = 0; nt < 4; ++nt) {
                int row = wn * 64 + nt * 16 + l15;
                int ph = (kk * 4 + quad) ^ (row & 7);
                bf[nt] = *(const v8h*)(&Bs[row * 64 + ph * 8]);
            }
            #pragma unroll
            for (int mt = 0; mt < 4; ++mt)
                #pragma unroll
                for (int nt = 0; nt < 4; ++nt)
                    acc[mt][nt] = __builtin_amdgcn_mfma_f32_16x16x32_f16(
                        af[mt], bf[nt], acc[mt][nt], 0, 0, 0);
        }
        __syncthreads();
    }
    // epilogue: s_scores[m] += sum_n tanh(acc + qp[n]) * v[n]  (partial over this np)
    float qpv[4], vv[4];
    #pragma unroll
    for (int nt = 0; nt < 4; ++nt) {
        int ng = n0 + wn * 64 + nt * 16 + l15;
        qpv[nt] = qp[b * H_DIM + ng];
        vv[nt]  = v[ng];
    }
    #pragma unroll
    for (int mt = 0; mt < 4; ++mt) {
        #pragma unroll
        for (int r = 0; r < 4; ++r) {
            float s = 0.f;
            #pragma unroll
            for (int nt = 0; nt < 4; ++nt) {
                float x = acc[mt][nt][r] + qpv[nt];
                float e = __expf(2.f * x);           // tanh(x) = 1 - 2/(e^{2x}+1)
                s += (1.f - 2.f / (e + 1.f)) * vv[nt];
            }
            s += __shfl_xor(s, 1);
            s += __shfl_xor(s, 2);
            s += __shfl_xor(s, 4);
            s += __shfl_xor(s, 8);
            if (l15 == 0)
                atomicAdd(&s_scores[wm * 64 + mt * 16 + quad * 4 + r], s);
        }
    }
    __syncthreads();
    if (tid < 128) atomicAdd(&scores[(size_t)b * S_DIM + m0 + tid], s_scores[tid]);
}

// ---------------- K2: row softmax -> attention weights (output 1) ----------------
__global__ void k_softmax(const float* __restrict__ scores, float* __restrict__ wout) {
    __shared__ float red[256];
    int b = blockIdx.x, tid = threadIdx.x;
    float ls[8];
    float lmax = -1e30f;
    #pragma unroll
    for (int i = 0; i < 8; ++i) {
        ls[i] = scores[b * S_DIM + i * 256 + tid];
        lmax = fmaxf(lmax, ls[i]);
    }
    red[tid] = lmax; __syncthreads();
    for (int st = 128; st > 0; st >>= 1) {
        if (tid < st) red[tid] = fmaxf(red[tid], red[tid + st]);
        __syncthreads();
    }
    float rowmax = red[0]; __syncthreads();
    float lsum = 0.f;
    #pragma unroll
    for (int i = 0; i < 8; ++i) { ls[i] = __expf(ls[i] - rowmax); lsum += ls[i]; }
    red[tid] = lsum; __syncthreads();
    for (int st = 128; st > 0; st >>= 1) {
        if (tid < st) red[tid] += red[tid + st];
        __syncthreads();
    }
    float inv = 1.f / red[0];
    #pragma unroll
    for (int i = 0; i < 8; ++i) wout[b * S_DIM + i * 256 + tid] = ls[i] * inv;
}

// ---------------- K3: context partials over S-chunks ----------------
template<bool AF16>
__global__ void k_ctx_part(const float* __restrict__ values, const _Float16* __restrict__ values16,
                           const float* __restrict__ w, float* __restrict__ part) {
    int b = blockIdx.x >> 4, sc = blockIdx.x & 15, tid = threadIdx.x;
    float4 acc = {0.f, 0.f, 0.f, 0.f};
    size_t base = ((size_t)b * S_DIM + sc * 128) * D_DIM;
    for (int s = 0; s < 128; ++s) {
        float ww = w[b * S_DIM + sc * 128 + s];
        if (AF16) {
            v4h hv = *(const v4h*)(values16 + base + (size_t)s * D_DIM + tid * 4);
            acc.x += ww * (float)hv[0]; acc.y += ww * (float)hv[1];
            acc.z += ww * (float)hv[2]; acc.w += ww * (float)hv[3];
        } else {
            float4 val = *(const float4*)(values + base + (size_t)s * D_DIM + tid * 4);
            acc.x += ww * val.x; acc.y += ww * val.y;
            acc.z += ww * val.z; acc.w += ww * val.w;
        }
    }
    *(float4*)(part + (size_t)(b * 16 + sc) * D_DIM + tid * 4) = acc;
}

// ---------------- K4: reduce partials -> context (output 0) ----------------
__global__ void k_ctx_reduce(const float* __restrict__ part, float* __restrict__ ctx) {
    int o = blockIdx.x * 256 + threadIdx.x;
    int b = o >> 10, d = o & 1023;
    float s = 0.f;
    #pragma unroll
    for (int sc = 0; sc < 16; ++sc) s += part[(size_t)(b * 16 + sc) * D_DIM + d];
    ctx[o] = s;
}

extern "C" void kernel_launch(void* const* d_in, const int* in_sizes, int n_in,
                              void* d_out, int out_size, void* d_ws, size_t ws_size,
                              hipStream_t stream) {
    const float* query  = (const float*)d_in[0];
    const float* values = (const float*)d_in[1];
    const float* W1     = (const float*)d_in[2];
    const float* W2     = (const float*)d_in[3];
    const float* v      = (const float*)d_in[4];

    char* ws = (char*)d_ws;
    bool f16path = ws_size >= (size_t)WS_NEED;

    _Float16* values16; _Float16* w1t; float* qp; float* scores; float* part;
    if (f16path) {
        values16 = (_Float16*)(ws + WS_V16);
        w1t      = (_Float16*)(ws + WS_W1T);
        qp       = (float*)(ws + WS_QP);
        scores   = (float*)(ws + WS_SCORES);
        part     = (float*)(ws + WS_PART);
    } else {
        values16 = nullptr;
        w1t      = (_Float16*)(ws);
        qp       = (float*)(ws + 2097152u);
        scores   = (float*)(ws + 2097152u + 131072u);
        part     = (float*)(ws + 2097152u + 131072u + 262144u);
    }

    float* ctx  = (float*)d_out;            // [32, 1024]
    float* wout = (float*)d_out + 32768;    // [32, 2048]

    hipMemsetAsync(scores, 0, 32 * 2048 * sizeof(float), stream);
    if (f16path) k_convert<<<dim3(32768), 256, 0, stream>>>(values, values16);
    k_w1t<<<dim3(16, 16), 256, 0, stream>>>(W1, w1t);
    k_qp<<<dim3(4, 32), 256, 0, stream>>>(query, W2, qp);
    if (f16path)
        k_scores<true><<<dim3(4096), 256, 0, stream>>>(values, values16, w1t, qp, v, scores);
    else
        k_scores<false><<<dim3(4096), 256, 0, stream>>>(values, values16, w1t, qp, v, scores);
    k_softmax<<<dim3(32), 256, 0, stream>>>(scores, wout);
    if (f16path)
        k_ctx_part<true><<<dim3(512), 256, 0, stream>>>(values, values16, wout, part);
    else
        k_ctx_part<false><<<dim3(512), 256, 0, stream>>>(values, values16, wout, part);
    k_ctx_reduce<<<dim3(128), 256, 0, stream>>>(part, ctx);
}

// Round 3
// 588.639 us; speedup vs baseline: 1.3231x; 1.1779x over previous
//
#include <hip/hip_runtime.h>
#include <hip/hip_fp16.h>

// Problem: B=32, S=2048, D=1024, H=1024
//   qp = query@W2 [B,H]; keys = values@W1 [B,S,H]; scores = tanh(qp+keys)@v [B,S]
//   w = softmax(scores); ctx = w@values [B,D]. Outputs: ctx (32768) ++ w (65536).

typedef _Float16 v8h __attribute__((ext_vector_type(8)));
typedef float    v4f __attribute__((ext_vector_type(4)));

#define B_DIM 32
#define S_DIM 2048
#define D_DIM 1024
#define H_DIM 1024

// workspace layout (bytes) -- total ~132.4 MiB (fits: f16 path ran in R2)
#define WS_V16    0u                       // [B][S][D] fp16 = 128 MiB (L3-resident)
#define WS_W1T    134217728u               // [H][D] fp16 = 2 MiB
#define WS_QP     (WS_W1T + 2097152u)      // [B][H] fp32
#define WS_SCORES (WS_QP + 131072u)        // [B][S] fp32 (atomicAdd target)
#define WS_PART   (WS_SCORES + 262144u)    // [B][16][D] fp32 = 2 MiB

// async global->LDS, 16B per lane; LDS dest = wave-uniform base + lane*16
__device__ __forceinline__ void gl_lds16(const _Float16* g, _Float16* l) {
    __builtin_amdgcn_global_load_lds(
        (const __attribute__((address_space(1))) void*)g,
        (__attribute__((address_space(3))) void*)l, 16, 0, 0);
}

// ---------------- K0: fused prep ----------------
// blocks [0,32768): values fp32 -> fp16 (non-temporal reads: don't evict the
//                   fp16 writes from L3 -- R2 showed 532 MB HBM re-fetch)
// blocks [32768,33024): W1 [D,H] -> W1T [H,D] fp16
// blocks [33024,33152): qp = query @ W2 (fp32, precision-critical)
// blocks [33152,33184): zero scores
__global__ void k_prep(const float* __restrict__ values, _Float16* __restrict__ v16,
                       const float* __restrict__ W1, _Float16* __restrict__ w1t,
                       const float* __restrict__ query, const float* __restrict__ W2,
                       float* __restrict__ qp, float* __restrict__ scores) {
    __shared__ float smem[64 * 65];
    int bid = blockIdx.x, tid = threadIdx.x;
    if (bid < 32768) {
        size_t i = ((size_t)bid * 256 + tid) * 8;
        v4f f0 = __builtin_nontemporal_load((const v4f*)(values + i));
        v4f f1 = __builtin_nontemporal_load((const v4f*)(values + i + 4));
        v8h hv;
        hv[0] = (_Float16)f0[0]; hv[1] = (_Float16)f0[1];
        hv[2] = (_Float16)f0[2]; hv[3] = (_Float16)f0[3];
        hv[4] = (_Float16)f1[0]; hv[5] = (_Float16)f1[1];
        hv[6] = (_Float16)f1[2]; hv[7] = (_Float16)f1[3];
        *(v8h*)(v16 + i) = hv;
    } else if (bid < 33024) {
        int j = bid - 32768;
        int h0 = (j & 15) * 64, d0 = (j >> 4) * 64;
        #pragma unroll
        for (int i = 0; i < 16; ++i) {
            int idx = i * 256 + tid;
            int dd = idx >> 6, hh = idx & 63;
            smem[dd * 65 + hh] = W1[(size_t)(d0 + dd) * H_DIM + h0 + hh];
        }
        __syncthreads();
        #pragma unroll
        for (int i = 0; i < 16; ++i) {
            int idx = i * 256 + tid;
            int hh = idx >> 6, dd = idx & 63;
            w1t[(size_t)(h0 + hh) * D_DIM + d0 + dd] = (_Float16)smem[dd * 65 + hh];
        }
    } else if (bid < 33152) {
        int j = bid - 33024;
        int hc = j & 3, b = j >> 2;
        #pragma unroll
        for (int i = 0; i < 4; ++i) smem[i * 256 + tid] = query[b * D_DIM + i * 256 + tid];
        __syncthreads();
        int h = hc * 256 + tid;
        float acc = 0.f;
        #pragma unroll 8
        for (int d = 0; d < D_DIM; ++d) acc += smem[d] * W2[(size_t)d * H_DIM + h];
        qp[b * H_DIM + h] = acc;
    } else {
        int j = bid - 33152;
        size_t o = (size_t)j * 2048 + tid * 8;
        *(v4f*)(scores + o)     = (v4f){0.f, 0.f, 0.f, 0.f};
        *(v4f*)(scores + o + 4) = (v4f){0.f, 0.f, 0.f, 0.f};
    }
}

// ---------------- K1: fused scores GEMM ----------------
// grid = B(32) x mtiles(16) x np(4) = 2048 blocks, 256 thr (2x2 waves)
// block tile 128(m) x 256(n), wave tile 64x128 (mt=4, nt=8), BK=64.
// Per kk: 12 ds_read_b128 (144 cyc) feed 32 MFMA (155 cyc) -> MFMA-bound issue mix.
// LDS rows = 64 halves, XOR-swizzle (kslot ^ row&7): global_load_lds forbids
// padding; swizzle keeps ds_read_b128 conflict-free (R2: SQ_LDS_BANK_CONFLICT=0).
__global__ __launch_bounds__(256, 2) void k_scores(
        const _Float16* __restrict__ values16, const _Float16* __restrict__ w1t,
        const float* __restrict__ qp, const float* __restrict__ v,
        float* __restrict__ scores) {
    __shared__ _Float16 As[128 * 64];   // 16 KiB
    __shared__ _Float16 Bs[256 * 64];   // 32 KiB
    __shared__ float s_scores[128];

    int tid = threadIdx.x;
    int wid = tid >> 6, lane = tid & 63;
    int quad = lane >> 4, l15 = lane & 15;
    int wm = wid >> 1, wn = wid & 1;

    int idx = blockIdx.x;
    int np  = idx & 3;
    int mtb = idx >> 2;
    int b   = mtb >> 4;
    int m0  = (mtb & 15) * 128;
    int n0  = np * 256;

    if (tid < 128) s_scores[tid] = 0.f;

    // per-thread staging constants
    int srow = lane >> 3;               // 0..7 within the wave's 8-row group
    int kg   = lane & 7;                // 16B chunk before swizzle
    const size_t arow = ((size_t)b * S_DIM + m0) * D_DIM;

    v4f acc[4][8];
    #pragma unroll
    for (int i = 0; i < 4; ++i)
        #pragma unroll
        for (int j = 0; j < 8; ++j) acc[i][j] = (v4f){0.f, 0.f, 0.f, 0.f};

    for (int kt = 0; kt < 16; ++kt) {
        int k0 = kt * 64;
        // stage A: 128 rows x 64 halves (4 wave-issues)
        #pragma unroll
        for (int i = 0; i < 4; ++i) {
            int brow = i * 32 + wid * 8;
            int row  = brow + srow;
            int kgs  = kg ^ (row & 7);
            gl_lds16(values16 + arow + (size_t)row * D_DIM + k0 + kgs * 8, &As[brow * 64]);
        }
        // stage B: 256 rows x 64 halves (8 wave-issues)
        #pragma unroll
        for (int i = 0; i < 8; ++i) {
            int brow = i * 32 + wid * 8;
            int row  = brow + srow;
            int kgs  = kg ^ (row & 7);
            gl_lds16(w1t + (size_t)(n0 + row) * D_DIM + k0 + kgs * 8, &Bs[brow * 64]);
        }
        __syncthreads();
        #pragma unroll
        for (int kk = 0; kk < 2; ++kk) {
            v8h af[4], bf[8];
            #pragma unroll
            for (int mt = 0; mt < 4; ++mt) {
                int row = wm * 64 + mt * 16 + l15;
                int ph  = (kk * 4 + quad) ^ (row & 7);
                af[mt] = *(const v8h*)(&As[row * 64 + ph * 8]);
            }
            #pragma unroll
            for (int nt = 0; nt < 8; ++nt) {
                int row = wn * 128 + nt * 16 + l15;
                int ph  = (kk * 4 + quad) ^ (row & 7);
                bf[nt] = *(const v8h*)(&Bs[row * 64 + ph * 8]);
            }
            #pragma unroll
            for (int mt = 0; mt < 4; ++mt)
                #pragma unroll
                for (int nt = 0; nt < 8; ++nt)
                    acc[mt][nt] = __builtin_amdgcn_mfma_f32_16x16x32_f16(
                        af[mt], bf[nt], acc[mt][nt], 0, 0, 0);
        }
        __syncthreads();
    }
    // epilogue: s_scores[m] += sum_n tanh(acc + qp[n]) * v[n]
    float qpv[8], vv[8];
    #pragma unroll
    for (int nt = 0; nt < 8; ++nt) {
        int ng = n0 + wn * 128 + nt * 16 + l15;
        qpv[nt] = qp[b * H_DIM + ng];
        vv[nt]  = v[ng];
    }
    #pragma unroll
    for (int mt = 0; mt < 4; ++mt) {
        #pragma unroll
        for (int r = 0; r < 4; ++r) {
            float s = 0.f;
            #pragma unroll
            for (int nt = 0; nt < 8; ++nt) {
                float x = acc[mt][nt][r] + qpv[nt];
                float e = __expf(2.f * x);           // tanh(x) = 1 - 2/(e^{2x}+1)
                s += (1.f - 2.f / (e + 1.f)) * vv[nt];
            }
            s += __shfl_xor(s, 1);
            s += __shfl_xor(s, 2);
            s += __shfl_xor(s, 4);
            s += __shfl_xor(s, 8);
            if (l15 == 0)
                atomicAdd(&s_scores[wm * 64 + mt * 16 + quad * 4 + r], s);
        }
    }
    __syncthreads();
    if (tid < 128) atomicAdd(&scores[(size_t)b * S_DIM + m0 + tid], s_scores[tid]);
}

// ---------------- K2: row softmax -> attention weights (output 1) ----------------
__global__ void k_softmax(const float* __restrict__ scores, float* __restrict__ wout) {
    __shared__ float red[256];
    int b = blockIdx.x, tid = threadIdx.x;
    float ls[8];
    float lmax = -1e30f;
    #pragma unroll
    for (int i = 0; i < 8; ++i) {
        ls[i] = scores[b * S_DIM + i * 256 + tid];
        lmax = fmaxf(lmax, ls[i]);
    }
    red[tid] = lmax; __syncthreads();
    for (int st = 128; st > 0; st >>= 1) {
        if (tid < st) red[tid] = fmaxf(red[tid], red[tid + st]);
        __syncthreads();
    }
    float rowmax = red[0]; __syncthreads();
    float lsum = 0.f;
    #pragma unroll
    for (int i = 0; i < 8; ++i) { ls[i] = __expf(ls[i] - rowmax); lsum += ls[i]; }
    red[tid] = lsum; __syncthreads();
    for (int st = 128; st > 0; st >>= 1) {
        if (tid < st) red[tid] += red[tid + st];
        __syncthreads();
    }
    float inv = 1.f / red[0];
    #pragma unroll
    for (int i = 0; i < 8; ++i) wout[b * S_DIM + i * 256 + tid] = ls[i] * inv;
}

// ---------------- K3: context partials over S-chunks ----------------
// grid = b(32) x sc(16); block processes 128 s-rows, 2 rows/iter via v8h loads.
__global__ void k_ctx_part(const _Float16* __restrict__ values16,
                           const float* __restrict__ w, float* __restrict__ part) {
    __shared__ float s_w[128];
    __shared__ float s_acc[128][8];
    int b = blockIdx.x >> 4, sc = blockIdx.x & 15, tid = threadIdx.x;
    if (tid < 128) s_w[tid] = w[b * S_DIM + sc * 128 + tid];
    __syncthreads();
    int half = tid >> 7, col = (tid & 127) * 8;
    float acc[8];
    #pragma unroll
    for (int j = 0; j < 8; ++j) acc[j] = 0.f;
    size_t base = ((size_t)(b * S_DIM + sc * 128 + half)) * D_DIM + col;
    #pragma unroll 4
    for (int it = 0; it < 64; ++it) {
        float ww = s_w[it * 2 + half];
        v8h hv = *(const v8h*)(values16 + base + (size_t)it * 2 * D_DIM);
        #pragma unroll
        for (int j = 0; j < 8; ++j) acc[j] += ww * (float)hv[j];
    }
    if (half == 1) {
        #pragma unroll
        for (int j = 0; j < 8; ++j) s_acc[tid & 127][j] = acc[j];
    }
    __syncthreads();
    if (half == 0) {
        #pragma unroll
        for (int j = 0; j < 8; ++j) acc[j] += s_acc[tid][j];
        float* dst = part + (size_t)(b * 16 + sc) * D_DIM + col;
        *(v4f*)dst = (v4f){acc[0], acc[1], acc[2], acc[3]};
        *(v4f*)(dst + 4) = (v4f){acc[4], acc[5], acc[6], acc[7]};
    }
}

// ---------------- K4: reduce partials -> context (output 0) ----------------
__global__ void k_ctx_reduce(const float* __restrict__ part, float* __restrict__ ctx) {
    int o = blockIdx.x * 256 + threadIdx.x;
    int b = o >> 10, d = o & 1023;
    float s = 0.f;
    #pragma unroll
    for (int sc = 0; sc < 16; ++sc) s += part[(size_t)(b * 16 + sc) * D_DIM + d];
    ctx[o] = s;
}

extern "C" void kernel_launch(void* const* d_in, const int* in_sizes, int n_in,
                              void* d_out, int out_size, void* d_ws, size_t ws_size,
                              hipStream_t stream) {
    const float* query  = (const float*)d_in[0];
    const float* values = (const float*)d_in[1];
    const float* W1     = (const float*)d_in[2];
    const float* W2     = (const float*)d_in[3];
    const float* v      = (const float*)d_in[4];

    char* ws = (char*)d_ws;
    _Float16* values16 = (_Float16*)(ws + WS_V16);
    _Float16* w1t      = (_Float16*)(ws + WS_W1T);
    float* qp          = (float*)(ws + WS_QP);
    float* scores      = (float*)(ws + WS_SCORES);
    float* part        = (float*)(ws + WS_PART);

    float* ctx  = (float*)d_out;            // [32, 1024]
    float* wout = (float*)d_out + 32768;    // [32, 2048]

    k_prep<<<dim3(33184), 256, 0, stream>>>(values, values16, W1, w1t, query, W2, qp, scores);
    k_scores<<<dim3(2048), 256, 0, stream>>>(values16, w1t, qp, v, scores);
    k_softmax<<<dim3(32), 256, 0, stream>>>(scores, wout);
    k_ctx_part<<<dim3(512), 256, 0, stream>>>(values16, wout, part);
    k_ctx_reduce<<<dim3(128), 256, 0, stream>>>(part, ctx);
}

// Round 4
// 580.638 us; speedup vs baseline: 1.3414x; 1.0138x over previous
//
#include <hip/hip_runtime.h>
#include <hip/hip_fp16.h>

// Problem: B=32, S=2048, D=1024, H=1024
//   qp = query@W2 [B,H]; keys = values@W1 [B,S,H]; scores = tanh(qp+keys)@v [B,S]
//   w = softmax(scores); ctx = w@values [B,D]. Outputs: ctx (32768) ++ w (65536).

typedef _Float16 v8h __attribute__((ext_vector_type(8)));
typedef float    v4f __attribute__((ext_vector_type(4)));

#define B_DIM 32
#define S_DIM 2048
#define D_DIM 1024
#define H_DIM 1024

// workspace layout (bytes) -- ~132.4 MiB
#define WS_V16    0u                       // [B][S][D] fp16 = 128 MiB (L3-resident)
#define WS_W1T    134217728u               // [H][D] fp16 = 2 MiB
#define WS_QP     (WS_W1T + 2097152u)      // [B][H] fp32
#define WS_SCORES (WS_QP + 131072u)        // [B][S] fp32 (atomicAdd target)

// async global->LDS, 16B per lane; LDS dest = wave-uniform base + lane*16
__device__ __forceinline__ void gl_lds16(const _Float16* g, _Float16* l) {
    __builtin_amdgcn_global_load_lds(
        (const __attribute__((address_space(1))) void*)g,
        (__attribute__((address_space(3))) void*)l, 16, 0, 0);
}

// ---------------- K0: fused prep ----------------
// blocks [0,32768): values fp32 -> fp16 (non-temporal reads: don't evict the
//                   fp16 writes from L3)
// blocks [32768,33024): W1 [D,H] -> W1T [H,D] fp16
// blocks [33024,33152): qp = query @ W2 (fp32, precision-critical)
// blocks [33152,33184): zero scores
__global__ void k_prep(const float* __restrict__ values, _Float16* __restrict__ v16,
                       const float* __restrict__ W1, _Float16* __restrict__ w1t,
                       const float* __restrict__ query, const float* __restrict__ W2,
                       float* __restrict__ qp, float* __restrict__ scores) {
    __shared__ float smem[64 * 65];
    int bid = blockIdx.x, tid = threadIdx.x;
    if (bid < 32768) {
        size_t i = ((size_t)bid * 256 + tid) * 8;
        v4f f0 = __builtin_nontemporal_load((const v4f*)(values + i));
        v4f f1 = __builtin_nontemporal_load((const v4f*)(values + i + 4));
        v8h hv;
        hv[0] = (_Float16)f0[0]; hv[1] = (_Float16)f0[1];
        hv[2] = (_Float16)f0[2]; hv[3] = (_Float16)f0[3];
        hv[4] = (_Float16)f1[0]; hv[5] = (_Float16)f1[1];
        hv[6] = (_Float16)f1[2]; hv[7] = (_Float16)f1[3];
        *(v8h*)(v16 + i) = hv;
    } else if (bid < 33024) {
        int j = bid - 32768;
        int h0 = (j & 15) * 64, d0 = (j >> 4) * 64;
        #pragma unroll
        for (int i = 0; i < 16; ++i) {
            int idx = i * 256 + tid;
            int dd = idx >> 6, hh = idx & 63;
            smem[dd * 65 + hh] = W1[(size_t)(d0 + dd) * H_DIM + h0 + hh];
        }
        __syncthreads();
        #pragma unroll
        for (int i = 0; i < 16; ++i) {
            int idx = i * 256 + tid;
            int hh = idx >> 6, dd = idx & 63;
            w1t[(size_t)(h0 + hh) * D_DIM + d0 + dd] = (_Float16)smem[dd * 65 + hh];
        }
    } else if (bid < 33152) {
        int j = bid - 33024;
        int hc = j & 3, b = j >> 2;
        #pragma unroll
        for (int i = 0; i < 4; ++i) smem[i * 256 + tid] = query[b * D_DIM + i * 256 + tid];
        __syncthreads();
        int h = hc * 256 + tid;
        float acc = 0.f;
        #pragma unroll 8
        for (int d = 0; d < D_DIM; ++d) acc += smem[d] * W2[(size_t)d * H_DIM + h];
        qp[b * H_DIM + h] = acc;
    } else {
        int j = bid - 33152;
        size_t o = (size_t)j * 2048 + tid * 8;
        *(v4f*)(scores + o)     = (v4f){0.f, 0.f, 0.f, 0.f};
        *(v4f*)(scores + o + 4) = (v4f){0.f, 0.f, 0.f, 0.f};
    }
}

// ---------------- K1: fused scores GEMM (unchanged from R3 -- at m97 plateau) ----------------
// grid = B(32) x mtiles(16) x np(4) = 2048 blocks, 256 thr (2x2 waves)
// block tile 128(m) x 256(n), wave tile 64x128 (mt=4, nt=8), BK=64.
__global__ __launch_bounds__(256, 2) void k_scores(
        const _Float16* __restrict__ values16, const _Float16* __restrict__ w1t,
        const float* __restrict__ qp, const float* __restrict__ v,
        float* __restrict__ scores) {
    __shared__ _Float16 As[128 * 64];   // 16 KiB
    __shared__ _Float16 Bs[256 * 64];   // 32 KiB
    __shared__ float s_scores[128];

    int tid = threadIdx.x;
    int wid = tid >> 6, lane = tid & 63;
    int quad = lane >> 4, l15 = lane & 15;
    int wm = wid >> 1, wn = wid & 1;

    int idx = blockIdx.x;
    int np  = idx & 3;
    int mtb = idx >> 2;
    int b   = mtb >> 4;
    int m0  = (mtb & 15) * 128;
    int n0  = np * 256;

    if (tid < 128) s_scores[tid] = 0.f;

    int srow = lane >> 3;
    int kg   = lane & 7;
    const size_t arow = ((size_t)b * S_DIM + m0) * D_DIM;

    v4f acc[4][8];
    #pragma unroll
    for (int i = 0; i < 4; ++i)
        #pragma unroll
        for (int j = 0; j < 8; ++j) acc[i][j] = (v4f){0.f, 0.f, 0.f, 0.f};

    for (int kt = 0; kt < 16; ++kt) {
        int k0 = kt * 64;
        #pragma unroll
        for (int i = 0; i < 4; ++i) {
            int brow = i * 32 + wid * 8;
            int row  = brow + srow;
            int kgs  = kg ^ (row & 7);
            gl_lds16(values16 + arow + (size_t)row * D_DIM + k0 + kgs * 8, &As[brow * 64]);
        }
        #pragma unroll
        for (int i = 0; i < 8; ++i) {
            int brow = i * 32 + wid * 8;
            int row  = brow + srow;
            int kgs  = kg ^ (row & 7);
            gl_lds16(w1t + (size_t)(n0 + row) * D_DIM + k0 + kgs * 8, &Bs[brow * 64]);
        }
        __syncthreads();
        #pragma unroll
        for (int kk = 0; kk < 2; ++kk) {
            v8h af[4], bf[8];
            #pragma unroll
            for (int mt = 0; mt < 4; ++mt) {
                int row = wm * 64 + mt * 16 + l15;
                int ph  = (kk * 4 + quad) ^ (row & 7);
                af[mt] = *(const v8h*)(&As[row * 64 + ph * 8]);
            }
            #pragma unroll
            for (int nt = 0; nt < 8; ++nt) {
                int row = wn * 128 + nt * 16 + l15;
                int ph  = (kk * 4 + quad) ^ (row & 7);
                bf[nt] = *(const v8h*)(&Bs[row * 64 + ph * 8]);
            }
            #pragma unroll
            for (int mt = 0; mt < 4; ++mt)
                #pragma unroll
                for (int nt = 0; nt < 8; ++nt)
                    acc[mt][nt] = __builtin_amdgcn_mfma_f32_16x16x32_f16(
                        af[mt], bf[nt], acc[mt][nt], 0, 0, 0);
        }
        __syncthreads();
    }
    float qpv[8], vv[8];
    #pragma unroll
    for (int nt = 0; nt < 8; ++nt) {
        int ng = n0 + wn * 128 + nt * 16 + l15;
        qpv[nt] = qp[b * H_DIM + ng];
        vv[nt]  = v[ng];
    }
    #pragma unroll
    for (int mt = 0; mt < 4; ++mt) {
        #pragma unroll
        for (int r = 0; r < 4; ++r) {
            float s = 0.f;
            #pragma unroll
            for (int nt = 0; nt < 8; ++nt) {
                float x = acc[mt][nt][r] + qpv[nt];
                float e = __expf(2.f * x);           // tanh(x) = 1 - 2/(e^{2x}+1)
                s += (1.f - 2.f / (e + 1.f)) * vv[nt];
            }
            s += __shfl_xor(s, 1);
            s += __shfl_xor(s, 2);
            s += __shfl_xor(s, 4);
            s += __shfl_xor(s, 8);
            if (l15 == 0)
                atomicAdd(&s_scores[wm * 64 + mt * 16 + quad * 4 + r], s);
        }
    }
    __syncthreads();
    if (tid < 128) atomicAdd(&scores[(size_t)b * S_DIM + m0 + tid], s_scores[tid]);
}

// ---------------- K2: fused softmax + context ----------------
// One block per batch row b (32 blocks x 1024 thr). Computes softmax exactly
// (full wout), then ctx = sum_s w_s * values16[b,s,:] over only the weights
// > 1e-7 (scores sigma ~13 -> softmax is winner-take-all; skipped mass
// <= 2048e-7 -> |ctx error| ~1e-3 << 8.2e-2 threshold). Compacted index list
// in LDS keeps the significant loop short (~tens of iterations).
__global__ __launch_bounds__(1024) void k_finish(
        const float* __restrict__ scores, const _Float16* __restrict__ values16,
        float* __restrict__ wout, float* __restrict__ ctx) {
    __shared__ float s_w[2048];
    __shared__ int   s_idx[2048];
    __shared__ float red[16];
    __shared__ float s_bcast;
    __shared__ int   s_cnt;

    int b = blockIdx.x, tid = threadIdx.x;
    int lane = tid & 63, wid = tid >> 6;

    float s0 = scores[b * S_DIM + tid];
    float s1 = scores[b * S_DIM + 1024 + tid];

    // --- row max ---
    float m = fmaxf(s0, s1);
    #pragma unroll
    for (int off = 1; off <= 32; off <<= 1) m = fmaxf(m, __shfl_xor(m, off));
    if (lane == 0) red[wid] = m;
    if (tid == 0) s_cnt = 0;
    __syncthreads();
    if (tid == 0) {
        float mm = red[0];
        #pragma unroll
        for (int i = 1; i < 16; ++i) mm = fmaxf(mm, red[i]);
        s_bcast = mm;
    }
    __syncthreads();
    float rowmax = s_bcast;

    // --- exp + row sum ---
    float e0 = __expf(s0 - rowmax);
    float e1 = __expf(s1 - rowmax);
    float sum = e0 + e1;
    #pragma unroll
    for (int off = 1; off <= 32; off <<= 1) sum += __shfl_xor(sum, off);
    if (lane == 0) red[wid] = sum;
    __syncthreads();
    if (tid == 0) {
        float ss = red[0];
        #pragma unroll
        for (int i = 1; i < 16; ++i) ss += red[i];
        s_bcast = 1.f / ss;
    }
    __syncthreads();
    float inv = s_bcast;

    float w0 = e0 * inv, w1 = e1 * inv;
    wout[b * S_DIM + tid]        = w0;
    wout[b * S_DIM + 1024 + tid] = w1;
    s_w[tid]        = w0;
    s_w[tid + 1024] = w1;

    // --- compact significant indices ---
    if (w0 > 1e-7f) { int p = atomicAdd(&s_cnt, 1); s_idx[p] = tid; }
    if (w1 > 1e-7f) { int p = atomicAdd(&s_cnt, 1); s_idx[p] = tid + 1024; }
    __syncthreads();
    int cnt = s_cnt;

    // --- context: thread tid owns column d=tid ---
    float acc = 0.f;
    const _Float16* vb = values16 + (size_t)b * S_DIM * D_DIM + tid;
    for (int i = 0; i < cnt; ++i) {
        int s = s_idx[i];
        acc += s_w[s] * (float)vb[(size_t)s * D_DIM];
    }
    ctx[b * D_DIM + tid] = acc;
}

extern "C" void kernel_launch(void* const* d_in, const int* in_sizes, int n_in,
                              void* d_out, int out_size, void* d_ws, size_t ws_size,
                              hipStream_t stream) {
    const float* query  = (const float*)d_in[0];
    const float* values = (const float*)d_in[1];
    const float* W1     = (const float*)d_in[2];
    const float* W2     = (const float*)d_in[3];
    const float* v      = (const float*)d_in[4];

    char* ws = (char*)d_ws;
    _Float16* values16 = (_Float16*)(ws + WS_V16);
    _Float16* w1t      = (_Float16*)(ws + WS_W1T);
    float* qp          = (float*)(ws + WS_QP);
    float* scores      = (float*)(ws + WS_SCORES);

    float* ctx  = (float*)d_out;            // [32, 1024]
    float* wout = (float*)d_out + 32768;    // [32, 2048]

    k_prep<<<dim3(33184), 256, 0, stream>>>(values, values16, W1, w1t, query, W2, qp, scores);
    k_scores<<<dim3(2048), 256, 0, stream>>>(values16, w1t, qp, v, scores);
    k_finish<<<dim3(32), 1024, 0, stream>>>(scores, values16, wout, ctx);
}